// Round 3
// baseline (1285.101 us; speedup 1.0000x reference)
//
#include <hip/hip_runtime.h>
#include <hip/hip_bf16.h>
#include <math.h>
#include <cstdint>

// ---------------------------------------------------------------------------
// 3-layer MLP (Linear+GELU ×3), bf16 MFMA compute, fp32 in/out.
//
// R3: R2's 256x256 8-phase counted-vmcnt schedule, with the obs fp32->bf16
// pre-pass DELETED and replaced by fused fp32-A reg-staging inside the
// pipeline (T14 issue-early / write-late):
//  - q0: issue 8x global_load_dwordx4 of A(t+1) into regs (fp32 path)
//  - q2: vmcnt(6) [exact: B1(t+1)2+av8+B0(t+2)2 -> av-lo landed],
//        cvt+swizzled ds_write half0 into buf[(t+1)&1]
//  - q3: MFMA first, then vmcnt(4) [av-hi + all older landed],
//        write half1, lgkmcnt(0) publish, barrier.
//  - All staging uses CLAMPED global source tile (min(t+x, NT-1)) with
//    UNCLAMPED destination parity -> uniform vmcnt counts through the tail
//    (no vmcnt(0) drain in-loop). Final-iter clamped stages land in regions
//    whose readers are barrier-retired or that are never read (verified).
//  - Region/barrier safety identical to R2 otherwise; ds_writes are fenced
//    by per-thread lgkmcnt(0) before the publishing barrier.
//  - Keep: chunk-XOR LDS swizzle (0 conflicts), XCD-chunked remap, j-inner
//    epilogue stores, exact-erf GELU, setprio around MFMA clusters.
// ---------------------------------------------------------------------------

typedef __bf16 bf16_t;
typedef __attribute__((ext_vector_type(8))) __bf16 bf16x8;
typedef __attribute__((ext_vector_type(4))) float f32x4;
typedef __attribute__((ext_vector_type(4))) unsigned short u16x4;

#define BK 64
#define TILE_ELEMS (256 * 64)   // one A or B tile (256 rows x 64 k) in elements

__device__ inline unsigned short f2bf_rne(float f) {
    unsigned int u = __builtin_bit_cast(unsigned int, f);
    u += 0x7fffu + ((u >> 16) & 1u);   // round-to-nearest-even
    return (unsigned short)(u >> 16);
}

__device__ inline float gelu_erf(float x) {
    return 0.5f * x * (1.0f + erff(x * 0.7071067811865475f));
}

__device__ inline void gload_lds16(const void* g, void* l) {
    auto gp = reinterpret_cast<const __attribute__((address_space(1))) unsigned int*>(
        reinterpret_cast<uintptr_t>(g));
    auto lp = reinterpret_cast<__attribute__((address_space(3))) unsigned int*>(
        reinterpret_cast<uintptr_t>(l));
    __builtin_amdgcn_global_load_lds(gp, lp, 16, 0, 0);
}

// ---- register-subtile loads / MFMA bursts (all indices compile-time) -------
#define LOADA(QM)                                                               \
    _Pragma("unroll") for (int i = 0; i < 4; ++i)                               \
    _Pragma("unroll") for (int s = 0; s < 2; ++s) {                             \
        const int r_ = wm + (QM) * 64 + i * 16 + lrow;                          \
        a_fr[i][s] = *(const bf16x8*)(cA + r_ * BK + (((s * 4 + quad) ^ swz) << 3)); \
    }

#define LOADB(DST, QN)                                                          \
    _Pragma("unroll") for (int j = 0; j < 2; ++j)                               \
    _Pragma("unroll") for (int s = 0; s < 2; ++s) {                             \
        const int r_ = wn + (QN) * 32 + j * 16 + lrow;                          \
        DST[j][s] = *(const bf16x8*)(cB + r_ * BK + (((s * 4 + quad) ^ swz) << 3)); \
    }

#define MMA16(QM, QN, BFR)                                                      \
    _Pragma("unroll") for (int i = 0; i < 4; ++i)                               \
    _Pragma("unroll") for (int j = 0; j < 2; ++j)                               \
    _Pragma("unroll") for (int s = 0; s < 2; ++s)                               \
        acc[(QM) * 4 + i][(QN) * 2 + j] = __builtin_amdgcn_mfma_f32_16x16x32_bf16( \
            a_fr[i][s], BFR[j][s], acc[(QM) * 4 + i][(QN) * 2 + j], 0, 0, 0);

// C = gelu(A[M,K] @ B[N,K]^T + bias), A fp32 (reg-staged) or bf16 (glds).
// Grid: (N/256, M/256), 512 threads = 8 waves (2M x 4N).
template <bool A_IS_FP32, bool OUT_BF16>
__global__ __launch_bounds__(512, 2)
void gemm_bias_gelu(const void* __restrict__ Av,
                    const bf16_t* __restrict__ B,     // [N,K] bf16
                    const float* __restrict__ bias,   // [N]
                    void* __restrict__ Cv,            // [M,N]
                    int M, int N, int K)
{
    __shared__ __align__(16) bf16_t lA[2 * TILE_ELEMS];   // 64 KiB
    __shared__ __align__(16) bf16_t lB[2 * TILE_ELEMS];   // 64 KiB

    const int tid  = threadIdx.x;
    const int wave = tid >> 6;
    const int lane = tid & 63;
    const int lrow = lane & 15;   // MFMA row/col within 16
    const int quad = lane >> 4;   // k-group of 8
    const int swz  = lrow & 7;    // read swizzle (row&7 == lrow&7)

    // ---- XCD-chunked remap (bijective: nwg % 8 == 0 for all layers)
    const int gx  = gridDim.x;
    const int nwg = gx * gridDim.y;
    int bid = blockIdx.y * gx + blockIdx.x;
    if ((nwg & 7) == 0) {
        const int cpx = nwg >> 3;
        bid = (bid & 7) * cpx + (bid >> 3);
    }
    const int col0 = (bid % gx) * 256;
    const int row0 = (bid / gx) * 256;

    const int wm = (wave >> 2) * 128;   // M-group: 2 waves of 128 rows
    const int wn = (wave & 3) * 64;     // N-group: 4 waves of 64 cols

    // glds staging: lane l fetches global chunk (l&7)^(l>>3) of row (l>>3)
    const int srow = lane >> 3;
    const int gchk = (lane & 7) ^ srow;

    const int NT    = K >> 6;
    const int lastT = NT - 1;
    const bf16_t* A0p = (const bf16_t*)Av + (size_t)row0 * K;  // bf16 path
    const float*  Afp = (const float*)Av + (size_t)row0 * K;   // fp32 path
    const bf16_t* B0p = B + (size_t)col0 * K;

    // stage one 128-row half of B (2 glds / thread). Source tile clamped,
    // dest parity UNclamped (tail-safe; see header comment).
    auto stageB_half = [&](int tile, int half) {
        const int st = tile < lastT ? tile : lastT;
        const int k0 = st << 6;
        const int rb = half * 128 + wave * 16;
        const bf16_t* g = B0p + (size_t)(rb + srow) * K + k0 + gchk * 8;
        bf16_t* l = lB + (tile & 1) * TILE_ELEMS + rb * BK;
        gload_lds16(g, l);
        gload_lds16(g + (size_t)8 * K, l + 8 * BK);
    };
    auto stageA_half_bf16 = [&](int tile, int half) {
        const int st = tile < lastT ? tile : lastT;
        const int k0 = st << 6;
        const int rb = half * 128 + wave * 16;
        const bf16_t* g = A0p + (size_t)(rb + srow) * K + k0 + gchk * 8;
        bf16_t* l = lA + (tile & 1) * TILE_ELEMS + rb * BK;
        gload_lds16(g, l);
        gload_lds16(g + (size_t)8 * K, l + 8 * BK);
    };

    // fp32-A reg staging: 8 float4/thread covers the full 256x64 tile
    // (c=0..3 -> rows 0..127 = half0, c=4..7 -> rows 128..255 = half1).
    float4 av[8];
    auto loadA_f32 = [&](int tile) {
        const int st = tile < lastT ? tile : lastT;
        const int k0 = st << 6;
        #pragma unroll
        for (int c = 0; c < 8; ++c) {
            const int e = c * 2048 + tid * 4;
            const int r = e >> 6;
            const int k = e & 63;
            av[c] = *(const float4*)(Afp + (size_t)r * K + k0 + k);
        }
    };
    auto writeA_f32_half = [&](int tile, int half) {
        bf16_t* dst = lA + (tile & 1) * TILE_ELEMS;
        #pragma unroll
        for (int c = half * 4; c < half * 4 + 4; ++c) {
            const int e = c * 2048 + tid * 4;
            const int r = e >> 6;
            const int k = e & 63;
            u16x4 h;
            h.x = f2bf_rne(av[c].x); h.y = f2bf_rne(av[c].y);
            h.z = f2bf_rne(av[c].z); h.w = f2bf_rne(av[c].w);
            const int off = r * BK + (((k >> 3) ^ (r & 7)) << 3) + (k & 7);
            *(u16x4*)(dst + off) = h;
        }
    };

    f32x4  acc[8][4] = {};
    bf16x8 a_fr[4][2];
    bf16x8 b_fr0[2][2], b_fr1[2][2];

    // ---- prologue: B(0), A(0), B(1); counted wait; publish tile 0 ---------
    stageB_half(0, 0); stageB_half(0, 1);
    if constexpr (A_IS_FP32) {
        loadA_f32(0);                                   // av(0) x8
    } else {
        stageA_half_bf16(0, 0); stageA_half_bf16(0, 1); // glds x4
    }
    stageB_half(1, 0); stageB_half(1, 1);
    asm volatile("s_waitcnt vmcnt(4)" ::: "memory");    // B(0)+A(0) landed; B(1) in flight
    if constexpr (A_IS_FP32) {
        writeA_f32_half(0, 0); writeA_f32_half(0, 1);
        asm volatile("s_waitcnt lgkmcnt(0)" ::: "memory");
    }
    __builtin_amdgcn_s_barrier();

    for (int t = 0; t < NT; ++t) {
        const bf16_t* cA = lA + (t & 1) * TILE_ELEMS;
        const bf16_t* cB = lB + (t & 1) * TILE_ELEMS;

        // -- q0: issue A(t+1) | read A(qm0), B(qn0) | MFMA (0,0)
        if constexpr (A_IS_FP32) loadA_f32(t + 1);          // 8 reg loads
        else                     stageA_half_bf16(t + 1, 0);
        LOADA(0)
        LOADB(b_fr0, 0)
        __builtin_amdgcn_s_barrier();
        asm volatile("s_waitcnt lgkmcnt(0)" ::: "memory");
        __builtin_amdgcn_s_setprio(1);
        MMA16(0, 0, b_fr0)
        __builtin_amdgcn_s_setprio(0);
        __builtin_amdgcn_s_barrier();

        // -- q1: (bf16: stage A1(t+1)) | read B(qn1) | MFMA (0,1)
        if constexpr (!A_IS_FP32) stageA_half_bf16(t + 1, 1);
        LOADB(b_fr1, 1)
        __builtin_amdgcn_s_barrier();
        asm volatile("s_waitcnt lgkmcnt(0)" ::: "memory");
        __builtin_amdgcn_s_setprio(1);
        MMA16(0, 1, b_fr1)
        __builtin_amdgcn_s_setprio(0);
        __builtin_amdgcn_s_barrier();

        // -- q2: stage B0(t+2) | (fp32: vmcnt(6), write A half0) | read A(qm1) | MFMA (1,0)
        stageB_half(t + 2, 0);
        LOADA(1)
        if constexpr (A_IS_FP32) {
            asm volatile("s_waitcnt vmcnt(6)" ::: "memory");  // av lo landed
            writeA_f32_half(t + 1, 0);
        }
        __builtin_amdgcn_s_barrier();
        asm volatile("s_waitcnt lgkmcnt(0)" ::: "memory");
        __builtin_amdgcn_s_setprio(1);
        MMA16(1, 0, b_fr0)
        __builtin_amdgcn_s_setprio(0);
        __builtin_amdgcn_s_barrier();

        // -- q3: stage B1(t+2) | MFMA (1,1) | counted vmcnt | (fp32: write A half1)
        stageB_half(t + 2, 1);
        __builtin_amdgcn_s_setprio(1);
        MMA16(1, 1, b_fr1)
        __builtin_amdgcn_s_setprio(0);
        asm volatile("s_waitcnt vmcnt(4)" ::: "memory");      // av hi + B(t+1) landed
        if constexpr (A_IS_FP32) {
            writeA_f32_half(t + 1, 1);
            asm volatile("s_waitcnt lgkmcnt(0)" ::: "memory"); // publish before barrier
        }
        __builtin_amdgcn_s_barrier();
    }
    asm volatile("s_waitcnt vmcnt(0)" ::: "memory");   // drain dead clamped stages

    // ---- epilogue: bias + exact-erf GELU + store (j innermost: adjacent
    // 32B segments of one row back-to-back -> L2 write-combining).
    float bv[4];
    #pragma unroll
    for (int nj = 0; nj < 4; ++nj) bv[nj] = bias[col0 + wn + nj * 16 + lrow];

    #pragma unroll
    for (int mi = 0; mi < 8; ++mi) {
        #pragma unroll
        for (int r = 0; r < 4; ++r) {
            const size_t row = (size_t)(row0 + wm + mi * 16 + quad * 4 + r);
            #pragma unroll
            for (int nj = 0; nj < 4; ++nj) {
                const int col = col0 + wn + nj * 16 + lrow;
                float v = acc[mi][nj][r] + bv[nj];
                v = gelu_erf(v);
                if constexpr (OUT_BF16)
                    ((unsigned short*)Cv)[row * N + col] = f2bf_rne(v);
                else
                    ((float*)Cv)[row * N + col] = v;
            }
        }
    }
}

__global__ void cvt_f32_to_bf16(const float* __restrict__ s,
                                unsigned short* __restrict__ d, int n4)
{
    const int i = blockIdx.x * 256 + threadIdx.x;
    if (i < n4) {
        const float4 v = ((const float4*)s)[i];
        u16x4 h;
        h.x = f2bf_rne(v.x); h.y = f2bf_rne(v.y);
        h.z = f2bf_rne(v.z); h.w = f2bf_rne(v.w);
        ((u16x4*)d)[i] = h;
    }
}

extern "C" void kernel_launch(void* const* d_in, const int* in_sizes, int n_in,
                              void* d_out, int out_size, void* d_ws, size_t ws_size,
                              hipStream_t stream)
{
    const int BATCH = 131072, OBS = 1024, H1 = 512, H2 = 512, H3 = 256;

    const float* obs = (const float*)d_in[0];
    const float* W1  = (const float*)d_in[1];
    const float* b1  = (const float*)d_in[2];
    const float* W2  = (const float*)d_in[3];
    const float* b2  = (const float*)d_in[4];
    const float* W3  = (const float*)d_in[5];
    const float* b3  = (const float*)d_in[6];
    float* out = (float*)d_out;

    // workspace (~258 MB): x1 | x2 | W1b | W2b | W3b
    char* ws = (char*)d_ws;
    bf16_t* x1  = (bf16_t*)ws;                                      // BATCH*H1
    bf16_t* x2  = (bf16_t*)(ws + (size_t)BATCH * H1 * 2);           // BATCH*H2
    bf16_t* w1b = (bf16_t*)(ws + (size_t)BATCH * (H1 + H2) * 2);
    bf16_t* w2b = w1b + (size_t)H1 * OBS;
    bf16_t* w3b = w2b + (size_t)H2 * H1;

    // weights fp32 -> bf16 (tiny)
    cvt_f32_to_bf16<<<dim3((H1 * OBS / 4 + 255) / 256), 256, 0, stream>>>(W1, (unsigned short*)w1b, H1 * OBS / 4);
    cvt_f32_to_bf16<<<dim3((H2 * H1 / 4 + 255) / 256), 256, 0, stream>>>(W2, (unsigned short*)w2b, H2 * H1 / 4);
    cvt_f32_to_bf16<<<dim3((H3 * H2 / 4 + 255) / 256), 256, 0, stream>>>(W3, (unsigned short*)w3b, H3 * H2 / 4);

    // L1: obs(fp32, fused reg-staged cvt) @ W1^T -> x1 (bf16)
    gemm_bias_gelu<true, true><<<dim3(H1 / 256, BATCH / 256), 512, 0, stream>>>(
        obs, w1b, b1, x1, BATCH, H1, OBS);
    // L2: x1 @ W2^T -> x2 (bf16)
    gemm_bias_gelu<false, true><<<dim3(H2 / 256, BATCH / 256), 512, 0, stream>>>(
        x1, w2b, b2, x2, BATCH, H2, H1);
    // L3: x2 @ W3^T -> out (fp32)
    gemm_bias_gelu<false, false><<<dim3(H3 / 256, BATCH / 256), 512, 0, stream>>>(
        x2, w3b, b3, out, BATCH, H3, H2);
}